// Round 10
// baseline (14294.704 us; speedup 1.0000x reference)
//
#include <hip/hip_runtime.h>
#include <stdint.h>

using short8 = __attribute__((ext_vector_type(8))) short;
using f32x4  = __attribute__((ext_vector_type(4))) float;
using uint4v = __attribute__((ext_vector_type(4))) unsigned;
typedef unsigned long long ull;

#define DEV static __device__ __forceinline__

DEV unsigned short f2bf(float f){
  unsigned u = __builtin_bit_cast(unsigned, f);
  u = (u + 0x7FFFu + ((u >> 16) & 1u)) >> 16;
  return (unsigned short)u;
}
DEV float bf2f(unsigned short v){
  return __builtin_bit_cast(float, ((unsigned)v) << 16);
}
DEV float sigm(float x){
  float e = __builtin_amdgcn_exp2f(-1.4426950408889634f * x);
  return __builtin_amdgcn_rcpf(1.0f + e);
}
DEV float tanh_(float x){
  float e = __builtin_amdgcn_exp2f(2.885390081777927f * x); // exp(2x)
  return 1.0f - 2.0f * __builtin_amdgcn_rcpf(e + 1.0f);
}

// LDS-only barrier: no vmcnt drain (publish stores stay in flight across it).
DEV void bar_lds(){
  __builtin_amdgcn_sched_barrier(0);
  asm volatile("s_waitcnt lgkmcnt(0)" ::: "memory");
  __builtin_amdgcn_s_barrier();
  __builtin_amdgcn_sched_barrier(0);
}

// fragment readiness: 4 ull = 8 tagged units; every tag halfword must equal pat
DEV int frag_ok(const ull d0, const ull d1, const ull d2, const ull d3, ull pat){
  const ull M = 0xFFFF0000FFFF0000ull;
  ull v = ((d0 & M) ^ pat) | ((d1 & M) ^ pat) | ((d2 & M) ^ pat) | ((d3 & M) ^ pat);
  return __all(v == 0);
}
DEV short8 unpack_h(const ull d0, const ull d1, const ull d2, const ull d3){
  uint4v u;
  u[0] = (unsigned)(d0 & 0xFFFFull) | ((unsigned)(d0 >> 32) << 16);
  u[1] = (unsigned)(d1 & 0xFFFFull) | ((unsigned)(d1 >> 32) << 16);
  u[2] = (unsigned)(d2 & 0xFFFFull) | ((unsigned)(d2 >> 32) << 16);
  u[3] = (unsigned)(d3 & 0xFFFFull) | ((unsigned)(d3 >> 32) << 16);
  return __builtin_bit_cast(short8, u);
}

// ---------------- aux kernels ----------------

__global__ void k_f32_to_bf16(const float* __restrict__ in, unsigned short* __restrict__ out, int n){
  int stride = gridDim.x * blockDim.x * 4;
  for (int i = (blockIdx.x * blockDim.x + threadIdx.x) * 4; i < n; i += stride){
    float4 v = *(const float4*)(in + i);
    ushort4 o4;
    o4.x = f2bf(v.x); o4.y = f2bf(v.y); o4.z = f2bf(v.z); o4.w = f2bf(v.w);
    *(ushort4*)(out + i) = o4;
  }
}

// bf16 + bf16 -> bf16 (enc fwd+bwd sum)
__global__ void k_add_bb(const unsigned short* __restrict__ a, const unsigned short* __restrict__ b,
                         unsigned short* __restrict__ out, int n){
  int stride = gridDim.x * blockDim.x * 8;
  for (int i = (blockIdx.x * blockDim.x + threadIdx.x) * 8; i < n; i += stride){
    short8 va = *(const short8*)(a + i);
    short8 vb = *(const short8*)(b + i);
    short8 o;
    #pragma unroll
    for (int j = 0; j < 8; ++j)
      o[j] = (short)f2bf(bf2f((unsigned short)va[j]) + bf2f((unsigned short)vb[j]));
    *(short8*)(out + i) = o;
  }
}

__global__ void k_add_f32(float* __restrict__ o, const float* __restrict__ b, int n){
  int stride = gridDim.x * blockDim.x * 4;
  for (int i = (blockIdx.x * blockDim.x + threadIdx.x) * 4; i < n; i += stride){
    float4 vo = *(const float4*)(o + i);
    float4 vb = *(const float4*)(b + i);
    vo.x += vb.x; vo.y += vb.y; vo.z += vb.z; vo.w += vb.w;
    *(float4*)(o + i) = vo;
  }
}

// Pack [k; r] (f32, [K,4U] each, K split KX|U) into per-(dir,wg,wave,ktile,ntile)
// MFMA B-fragment order (BLOCKED K split: wave w owns ktiles 6w..6w+5)
__global__ void k_pack(const float* __restrict__ k0, const float* __restrict__ r0,
                       const float* __restrict__ k1, const float* __restrict__ r1,
                       unsigned short* __restrict__ out, int E, int KX, int U){
  int n = 2 * E;
  int stride = gridDim.x * blockDim.x;
  for (int i = blockIdx.x * blockDim.x + threadIdx.x; i < n; i += stride){
    int d = i / E, r = i % E;
    const float* Km = d ? k1 : k0;
    const float* Rm = d ? r1 : r0;
    int j    = r & 7;  int q = r >> 3;
    int lane = q & 63; q >>= 6;
    int nt   = q & 3;  q >>= 2;
    int kt   = q % 6;  q /= 6;
    int w    = q & 3;  int wg = q >> 2;
    int k    = (w*6 + kt)*32 + ((lane >> 4) << 3) + j;   // blocked split
    int col  = nt * U + wg*16 + (lane & 15);             // gate-major column
    float v  = (k < KX) ? Km[(size_t)k * (4*U) + col]
                        : Rm[(size_t)(k - KX) * (4*U) + col];
    out[i] = f2bf(v);
  }
}

// ---------------- persistent recurrence kernel ----------------
// 1-RT tagged h exchange:
//   hb2[par][row][unit] = u32 { bf16(h) | (step+1)<<16 }.
//   Producers: fire-and-forget relaxed agent-scope stores in the gate loop.
//   Consumers: speculative b64 loads issued at step start, first check after
//   the x MFMAs, then per-fragment retry with s_sleep(4) backoff (only stale
//   fragments reloaded). Readiness and data arrive in the SAME round trip.
// Skew safety: each WG's h-waves collectively read ALL units (blocked split
// covers the full U range), so a producer reaching step s+2 implies every WG
// consumed step s -> parity slots are never overwritten under a reader.
// Replay safety: h is bit-identical across replays; memset clears poison tags.
// No counters, no flags, no vmcnt drains; both barriers are LDS-only.
// OBF: bf16 outputs (encoder) vs f32 (decoder).
template<int KX, int U, int WGS, bool OBF>
__global__ __launch_bounds__(256, 1)
void lstm_rec(const unsigned short* __restrict__ xab,    // [64][512][KX] bf16
              const unsigned short* __restrict__ packedB,
              const float* __restrict__ bias_f,
              const float* __restrict__ bias_b,
              const int*   __restrict__ sizes,
              unsigned* __restrict__ hbuf2,              // [2 dirs][2 par][64][U] u32
              void* __restrict__ out_f,                  // [64][512][U]
              void* __restrict__ out_b)
{
  constexpr int KTW = 6;             // ktiles per wave (blocked)
  constexpr int T   = 512;

  const int tid  = threadIdx.x;
  const int w    = tid >> 6;
  const int lane = tid & 63;
  const int dir  = (blockIdx.x >= WGS) ? 1 : 0;
  const int wg   = dir ? (int)blockIdx.x - WGS : (int)blockIdx.x;

  const unsigned short* pB = packedB + (size_t)dir * ((size_t)WGS*4*KTW*4*512)
                                     + (size_t)((wg*4 + w)*KTW)*4*512;
  unsigned* hb2     = hbuf2 + (size_t)dir * (2*64*U);
  const float* bias = dir ? bias_b : bias_f;
  void* outp        = dir ? out_b : out_f;

  // preload B fragments (step-invariant): 96 VGPRs
  short8 bfr[KTW][4];
  #pragma unroll
  for (int kt = 0; kt < KTW; ++kt)
    #pragma unroll
    for (int nt = 0; nt < 4; ++nt)
      bfr[kt][nt] = *(const short8*)(pB + ((kt*4 + nt)*512) + lane*8);

  // gate-phase ownership: unit u_l (0..15), rows rb..rb+3
  const int u_l = tid & 15;
  const int rb  = (tid >> 4) * 4;
  const int ug  = wg*16 + u_l;
  float bz[4]; int sz[4];
  #pragma unroll
  for (int g = 0; g < 4; ++g) bz[g] = bias[g*U + ug];
  #pragma unroll
  for (int r = 0; r < 4; ++r) sz[r] = sizes[rb + r];
  float c[4]    = {0.f,0.f,0.f,0.f};
  float hreg[4] = {0.f,0.f,0.f,0.f};

  __shared__ float part[4][64][68];

  const int arow  = lane & 15;         // A-frag row / D-frag col within tile
  const int kgrp  = (lane >> 4) * 8;   // A-frag k offset within ktile
  const int rquad = (lane >> 4) * 4;   // D-frag row base

  // unified A-fragment buffer: x tiles use slots [0..1] as short8 (16B);
  // h tiles use all 4 ull (tagged, 32B -> 16B after unpack)
  ull abuf[KTW][4][4];

  // x prefetch for step 0
  {
    const int t0 = dir ? T - 1 : 0;
    #pragma unroll
    for (int kt = 0; kt < KTW; ++kt){
      const int kg = (w*KTW + kt) * 32;
      if (kg < KX){
        #pragma unroll
        for (int mt = 0; mt < 4; ++mt)
          *(short8*)&abuf[kt][mt][0] =
            *(const short8*)(xab + ((size_t)((mt*16 + arow)*T + t0))*KX + (kg + kgrp));
      }
    }
  }

  for (int s = 0; s < T; ++s){
    const int t   = dir ? (T - 1 - s) : s;
    const int par = s & 1;
    const unsigned* hb2r = hb2 + (size_t)par*64*U;
    const ull tag = (ull)(unsigned)s;
    const ull pat = (tag << 16) | (tag << 48);

    // ---- A: speculative tagged h loads (issued before x MFMAs) ----
    unsigned hmask = 0;
    if (s > 0){
      #pragma unroll
      for (int kt = 0; kt < KTW; ++kt){
        const int kg = (w*KTW + kt) * 32;
        if (kg >= KX){
          #pragma unroll
          for (int mt = 0; mt < 4; ++mt){
            const ull* hp = (const ull*)(hb2r + (size_t)(mt*16 + arow)*U + (kg - KX + kgrp));
            #pragma unroll
            for (int j = 0; j < 4; ++j)
              abuf[kt][mt][j] = __hip_atomic_load(hp + j, __ATOMIC_RELAXED, __HIP_MEMORY_SCOPE_AGENT);
            hmask |= 1u << (kt*4 + mt);
          }
        }
      }
    }

    f32x4 acc[4][4];
    #pragma unroll
    for (int mt = 0; mt < 4; ++mt)
      #pragma unroll
      for (int nt = 0; nt < 4; ++nt)
        acc[mt][nt] = (f32x4){0.f, 0.f, 0.f, 0.f};

    // ---- B: x MFMAs (overlap the h-load round trip) ----
    #pragma unroll
    for (int kt = 0; kt < KTW; ++kt){
      const int kg = (w*KTW + kt) * 32;
      if (kg < KX){
        #pragma unroll
        for (int mt = 0; mt < 4; ++mt){
          short8 a = *(short8*)&abuf[kt][mt][0];
          #pragma unroll
          for (int nt = 0; nt < 4; ++nt)
            acc[mt][nt] = __builtin_amdgcn_mfma_f32_16x16x32_bf16(a, bfr[kt][nt], acc[mt][nt], 0, 0, 0);
        }
      }
    }

    if (hmask){
      // ---- C: per-fragment tag check; backoff BEFORE any reload ----
      unsigned bad = hmask;
      for (;;){
        unsigned nbad = 0;
        #pragma unroll
        for (int kt = 0; kt < KTW; ++kt){
          const int kg = (w*KTW + kt) * 32;
          if (kg >= KX){
            #pragma unroll
            for (int mt = 0; mt < 4; ++mt){
              const unsigned f = 1u << (kt*4 + mt);
              if (bad & f)
                if (!frag_ok(abuf[kt][mt][0], abuf[kt][mt][1], abuf[kt][mt][2], abuf[kt][mt][3], pat))
                  nbad |= f;
            }
          }
        }
        if (!nbad) break;
        __builtin_amdgcn_s_sleep(4);      // backoff: no retry storm
        #pragma unroll
        for (int kt = 0; kt < KTW; ++kt){
          const int kg = (w*KTW + kt) * 32;
          if (kg >= KX){
            #pragma unroll
            for (int mt = 0; mt < 4; ++mt){
              const unsigned f = 1u << (kt*4 + mt);
              if (nbad & f){
                const ull* hp = (const ull*)(hb2r + (size_t)(mt*16 + arow)*U + (kg - KX + kgrp));
                #pragma unroll
                for (int j = 0; j < 4; ++j)
                  abuf[kt][mt][j] = __hip_atomic_load(hp + j, __ATOMIC_RELAXED, __HIP_MEMORY_SCOPE_AGENT);
              }
            }
          }
        }
        bad = nbad;
      }
      // ---- D: unpack + h MFMAs ----
      #pragma unroll
      for (int kt = 0; kt < KTW; ++kt){
        const int kg = (w*KTW + kt) * 32;
        if (kg >= KX){
          #pragma unroll
          for (int mt = 0; mt < 4; ++mt){
            short8 a = unpack_h(abuf[kt][mt][0], abuf[kt][mt][1], abuf[kt][mt][2], abuf[kt][mt][3]);
            #pragma unroll
            for (int nt = 0; nt < 4; ++nt)
              acc[mt][nt] = __builtin_amdgcn_mfma_f32_16x16x32_bf16(a, bfr[kt][nt], acc[mt][nt], 0, 0, 0);
          }
        }
      }
    }

    // ---- E: D-frag scatter (b128) ----
    #pragma unroll
    for (int mt = 0; mt < 4; ++mt)
      #pragma unroll
      for (int nt = 0; nt < 4; ++nt)
        *(f32x4*)&part[w][nt*16 + arow][mt*16 + rquad] = acc[mt][nt];

    bar_lds();   // scatter visible to gate readers

    // ---- G: gate phase + tagged publish ----
    f32x4 zg[4];
    #pragma unroll
    for (int g = 0; g < 4; ++g){
      const int cb = g*16 + u_l;
      f32x4 v = *(const f32x4*)&part[0][cb][rb];
      #pragma unroll
      for (int ww = 1; ww < 4; ++ww)
        v += *(const f32x4*)&part[ww][cb][rb];
      zg[g] = v;
    }

    unsigned* hb2w = hb2 + (size_t)(par ^ 1)*64*U;
    const unsigned utag = (unsigned)(s + 1) << 16;
    #pragma unroll
    for (int r = 0; r < 4; ++r){
      float ig = sigm (zg[0][r] + bz[0]);
      float fg = sigm (zg[1][r] + bz[1]);
      float gg = tanh_(zg[2][r] + bz[2]);
      float og = sigm (zg[3][r] + bz[3]);
      float cn = fg * c[r] + ig * gg;
      float hn = og * tanh_(cn);
      bool m  = (t < sz[r]);
      c[r] = m ? cn : c[r];
      float h = m ? hn : hreg[r];
      hreg[r] = h;
      if (s != T - 1)
        __hip_atomic_store(hb2w + (size_t)(rb + r)*U + ug,
                           (unsigned)f2bf(h) | utag,
                           __ATOMIC_RELAXED, __HIP_MEMORY_SCOPE_AGENT);
    }

    bar_lds();   // gate reads done before next step's scatter (LDS-only)

    // ---- out stores (acks overlap next step) ----
    #pragma unroll
    for (int r = 0; r < 4; ++r){
      const size_t oi = ((size_t)(rb + r)*T + t)*U + ug;
      if constexpr (OBF) ((unsigned short*)outp)[oi] = f2bf(hreg[r]);
      else               ((float*)outp)[oi] = hreg[r];
    }

    // ---- x prefetch for next step ----
    if (s != T - 1){
      const int tn = dir ? t - 1 : t + 1;
      #pragma unroll
      for (int kt = 0; kt < KTW; ++kt){
        const int kg = (w*KTW + kt) * 32;
        if (kg < KX){
          #pragma unroll
          for (int mt = 0; mt < 4; ++mt)
            *(short8*)&abuf[kt][mt][0] =
              *(const short8*)(xab + ((size_t)((mt*16 + arow)*T + tn))*KX + (kg + kgrp));
        }
      }
    }
  }
}

// ---------------- launch ----------------

extern "C" void kernel_launch(void* const* d_in, const int* in_sizes, int n_in,
                              void* d_out, int out_size, void* d_ws, size_t ws_size,
                              hipStream_t stream){
  const float* x      = (const float*)d_in[0];
  const int*   sizes  = (const int*)  d_in[1];
  const float* enc_kf = (const float*)d_in[2];
  const float* enc_rf = (const float*)d_in[3];
  const float* enc_bf = (const float*)d_in[4];
  const float* enc_kb = (const float*)d_in[5];
  const float* enc_rb = (const float*)d_in[6];
  const float* enc_bb = (const float*)d_in[7];
  const float* dec_kf = (const float*)d_in[8];
  const float* dec_rf = (const float*)d_in[9];
  const float* dec_bf = (const float*)d_in[10];
  const float* dec_kb = (const float*)d_in[11];
  const float* dec_rb = (const float*)d_in[12];
  const float* dec_bb = (const float*)d_in[13];
  float* out = (float*)d_out;
  char*  ws  = (char*)d_ws;

  const size_t o_xbf  = 0;                        // 33,554,432  x bf16 [64][512][512]
  const size_t o_esum = o_xbf  + 33554432ull;     // 16,777,216  enc fwd+bwd sum bf16
  const size_t o_pBe  = o_esum + 16777216ull;     //  3,145,728  packed enc [k;r]
  const size_t o_pBd  = o_pBe  + 3145728ull;      //  6,291,456  packed dec [k;r]
  const size_t o_ehf  = o_pBd  + 6291456ull;      // 16,777,216  enc fwd h bf16
  const size_t o_ehb  = o_ehf  + 16777216ull;     // 16,777,216  enc bwd h bf16
  const size_t o_dhb  = o_ehb  + 16777216ull;     // 67,108,864  dec bwd h f32
  const size_t o_hb2e = o_dhb  + 67108864ull;     //    262,144  enc tagged h exchange
  const size_t o_hb2d = o_hb2e + 262144ull;       //    524,288  dec tagged h exchange
  const size_t total  = o_hb2d + 524288ull;       // ~161.2 MB
  if (ws_size < total) return;

  unsigned short* xbf  = (unsigned short*)(ws + o_xbf);
  unsigned short* esum = (unsigned short*)(ws + o_esum);
  unsigned short* pBe  = (unsigned short*)(ws + o_pBe);
  unsigned short* pBd  = (unsigned short*)(ws + o_pBd);
  unsigned short* ehf  = (unsigned short*)(ws + o_ehf);
  unsigned short* ehb  = (unsigned short*)(ws + o_ehb);
  float*          dhb  = (float*)(ws + o_dhb);
  unsigned*       hb2e = (unsigned*)(ws + o_hb2e);
  unsigned*       hb2d = (unsigned*)(ws + o_hb2d);

  // zero h-exchange tags every call (clears the 0xAA poison; consumers then
  // wait for fresh publishes; replayed values are bit-identical anyway)
  hipMemsetAsync(ws + o_hb2e, 0, 262144ull + 524288ull, stream);

  // x -> bf16
  k_f32_to_bf16<<<2048, 256, 0, stream>>>(x, xbf, 64*512*512);

  // pack weights (blocked K split)
  k_pack<<<2048, 256, 0, stream>>>(enc_kf, enc_rf, enc_kb, enc_rb, pBe, 786432, 512, 256);
  k_pack<<<2048, 256, 0, stream>>>(dec_kf, dec_rf, dec_kb, dec_rb, pBd, 1572864, 256, 512);

  // encoder bilstm (fwd 16 WGs + bwd 16 WGs), bf16 outputs
  lstm_rec<512, 256, 16, true><<<32, 256, 0, stream>>>(xbf, pBe, enc_bf, enc_bb, sizes,
                                                       hb2e, ehf, ehb);
  // enc_sum = bf16(hf + hb)
  k_add_bb<<<2048, 256, 0, stream>>>(ehf, ehb, esum, 64*512*256);

  // decoder bilstm: fwd writes d_out f32, bwd to ws
  lstm_rec<256, 512, 32, false><<<64, 256, 0, stream>>>(esum, pBd, dec_bf, dec_bb, sizes,
                                                        hb2d, out, dhb);
  // d_out += dec bwd
  k_add_f32<<<2048, 256, 0, stream>>>(out, dhb, 64*512*512);
}

// Round 11
// 8596.405 us; speedup vs baseline: 1.6629x; 1.6629x over previous
//
#include <hip/hip_runtime.h>
#include <stdint.h>

using short8 = __attribute__((ext_vector_type(8))) short;
using f32x4  = __attribute__((ext_vector_type(4))) float;
typedef unsigned long long ull;

#define DEV static __device__ __forceinline__

DEV unsigned short f2bf(float f){
  unsigned u = __builtin_bit_cast(unsigned, f);
  u = (u + 0x7FFFu + ((u >> 16) & 1u)) >> 16;
  return (unsigned short)u;
}
DEV float sigm(float x){
  float e = __builtin_amdgcn_exp2f(-1.4426950408889634f * x);
  return __builtin_amdgcn_rcpf(1.0f + e);
}
DEV float tanh_(float x){
  float e = __builtin_amdgcn_exp2f(2.885390081777927f * x); // exp(2x)
  return 1.0f - 2.0f * __builtin_amdgcn_rcpf(e + 1.0f);
}

// LDS-only barrier: NO vmcnt drain (out-store/prefetch acks never block a step).
DEV void bar_lds(){
  __builtin_amdgcn_sched_barrier(0);
  asm volatile("s_waitcnt lgkmcnt(0)" ::: "memory");
  __builtin_amdgcn_s_barrier();
  __builtin_amdgcn_sched_barrier(0);
}

// ---------------- aux kernels ----------------

__global__ void k_f32_to_bf16(const float* __restrict__ in, unsigned short* __restrict__ out, int n){
  int stride = gridDim.x * blockDim.x * 4;
  for (int i = (blockIdx.x * blockDim.x + threadIdx.x) * 4; i < n; i += stride){
    float4 v = *(const float4*)(in + i);
    ushort4 o4;
    o4.x = f2bf(v.x); o4.y = f2bf(v.y); o4.z = f2bf(v.z); o4.w = f2bf(v.w);
    *(ushort4*)(out + i) = o4;
  }
}

__global__ void k_add_bf16(const float* __restrict__ a, const float* __restrict__ b,
                           unsigned short* __restrict__ out, int n){
  int stride = gridDim.x * blockDim.x * 4;
  for (int i = (blockIdx.x * blockDim.x + threadIdx.x) * 4; i < n; i += stride){
    float4 va = *(const float4*)(a + i);
    float4 vb = *(const float4*)(b + i);
    ushort4 o4;
    o4.x = f2bf(va.x + vb.x); o4.y = f2bf(va.y + vb.y);
    o4.z = f2bf(va.z + vb.z); o4.w = f2bf(va.w + vb.w);
    *(ushort4*)(out + i) = o4;
  }
}

__global__ void k_add_f32(float* __restrict__ o, const float* __restrict__ b, int n){
  int stride = gridDim.x * blockDim.x * 4;
  for (int i = (blockIdx.x * blockDim.x + threadIdx.x) * 4; i < n; i += stride){
    float4 vo = *(const float4*)(o + i);
    float4 vb = *(const float4*)(b + i);
    vo.x += vb.x; vo.y += vb.y; vo.z += vb.z; vo.w += vb.w;
    *(float4*)(o + i) = vo;
  }
}

// Pack [k; r] (f32, [K,4U] each, K split KX|U) into per-(dir,wg,wave,ktile,ntile)
// MFMA B-fragment order (BLOCKED K split: wave w owns ktiles 6w..6w+5)
__global__ void k_pack(const float* __restrict__ k0, const float* __restrict__ r0,
                       const float* __restrict__ k1, const float* __restrict__ r1,
                       unsigned short* __restrict__ out, int E, int KX, int U){
  int n = 2 * E;
  int stride = gridDim.x * blockDim.x;
  for (int i = blockIdx.x * blockDim.x + threadIdx.x; i < n; i += stride){
    int d = i / E, r = i % E;
    const float* Km = d ? k1 : k0;
    const float* Rm = d ? r1 : r0;
    int j    = r & 7;  int q = r >> 3;
    int lane = q & 63; q >>= 6;
    int nt   = q & 3;  q >>= 2;
    int kt   = q % 6;  q /= 6;
    int w    = q & 3;  int wg = q >> 2;
    int k    = (w*6 + kt)*32 + ((lane >> 4) << 3) + j;
    int col  = nt * U + wg*16 + (lane & 15);   // gate-major global column
    float v  = (k < KX) ? Km[(size_t)k * (4*U) + col]
                        : Rm[(size_t)(k - KX) * (4*U) + col];
    out[i] = f2bf(v);
  }
}

// ---------------- persistent recurrence kernel ----------------
// R5 skeleton; sync re-engineered:
//  - packed per-WAVE flag words (NF = WGS*4 consecutive u32 = 2-4 cache lines):
//    plain relaxed agent stores, NO atomic RMW, broadcast-friendly coalesced poll
//    (lane i loads word i -> 2 LLC requests total), first attempt issued before
//    the x MFMAs.
//  - publish path: h sc1 stores -> per-wave s_waitcnt vmcnt(0) (drains ONLY this
//    wave's h acks; prior out/prefetch acks are ~2.5us old) -> lane0 flag store.
//  - both intra-step barriers are LDS-only: NO full-WG vmcnt drain anywhere.
// Consumers wait for ALL NF flags >= s, then load h (relaxed agent atomics).
// Skew bound <2 steps (all-to-all coverage) -> parity slots never overwritten
// under a reader.
template<int KX, int U, int WGS>
__global__ __launch_bounds__(256, 1)
void lstm_rec(const unsigned short* __restrict__ xab,    // [64][512][KX] bf16
              const unsigned short* __restrict__ packedB,
              const float* __restrict__ bias_f,
              const float* __restrict__ bias_b,
              const int*   __restrict__ sizes,
              unsigned short* __restrict__ hbuf,         // [2 dirs][2][64][U] bf16
              unsigned* __restrict__ flags,              // [2 dirs][128] u32 packed
              float* __restrict__ out_f,                 // [64][512][U]
              float* __restrict__ out_b)
{
  constexpr int KTW = 6;               // ktiles per wave (blocked)
  constexpr int T   = 512;
  constexpr int NF  = WGS * 4;         // per-wave flag words (64 or 128)

  const int tid  = threadIdx.x;
  const int w    = tid >> 6;
  const int lane = tid & 63;
  const int dir  = (blockIdx.x >= WGS) ? 1 : 0;
  const int wg   = dir ? (int)blockIdx.x - WGS : (int)blockIdx.x;

  const unsigned short* pB = packedB + (size_t)dir * ((size_t)WGS*4*KTW*4*512)
                                     + (size_t)((wg*4 + w)*KTW)*4*512;
  unsigned short* hb  = hbuf + (size_t)dir * (2*64*U);
  unsigned*       flg = flags + dir * 128;
  const float* bias = dir ? bias_b : bias_f;
  float* outp       = dir ? out_b : out_f;

  const bool has_h = ((w*KTW + KTW - 1) * 32) >= KX;

  // preload B fragments (step-invariant): 96 VGPRs
  short8 bfr[KTW][4];
  #pragma unroll
  for (int kt = 0; kt < KTW; ++kt)
    #pragma unroll
    for (int nt = 0; nt < 4; ++nt)
      bfr[kt][nt] = *(const short8*)(pB + ((kt*4 + nt)*512) + lane*8);

  // gate-phase ownership: unit u_l (0..15), rows rb..rb+3
  const int u_l = tid & 15;
  const int rb  = (tid >> 4) * 4;
  const int ug  = wg*16 + u_l;
  float bz[4]; int sz[4];
  #pragma unroll
  for (int g = 0; g < 4; ++g) bz[g] = bias[g*U + ug];
  #pragma unroll
  for (int r = 0; r < 4; ++r) sz[r] = sizes[rb + r];
  float c[4]    = {0.f,0.f,0.f,0.f};
  float hreg[4] = {0.f,0.f,0.f,0.f};

  __shared__ float part[4][64][68];

  const int arow  = lane & 15;
  const int kgrp  = (lane >> 4) * 8;
  const int rquad = (lane >> 4) * 4;

  // x fragments, prefetched one step ahead
  short8 xreg[KTW][4];
  {
    const int t0 = dir ? T - 1 : 0;
    #pragma unroll
    for (int kt = 0; kt < KTW; ++kt){
      const int kg = (w*KTW + kt) * 32;
      if (kg < KX){
        #pragma unroll
        for (int mt = 0; mt < 4; ++mt)
          xreg[kt][mt] = *(const short8*)(xab + ((size_t)((mt*16 + arow)*T + t0))*KX + (kg + kgrp));
      }
    }
  }

  for (int s = 0; s < T; ++s){
    const int t   = dir ? (T - 1 - s) : s;
    const int par = s & 1;

    // ---- pre-issue first flag gather (overlaps x MFMAs) ----
    unsigned pv0 = 0, pv1 = 0;
    const bool polling = (s > 0) && has_h;
    if (polling){
      pv0 = __hip_atomic_load(&flg[lane], __ATOMIC_RELAXED, __HIP_MEMORY_SCOPE_AGENT);
      if constexpr (NF > 64)
        pv1 = __hip_atomic_load(&flg[lane + 64], __ATOMIC_RELAXED, __HIP_MEMORY_SCOPE_AGENT);
    }

    f32x4 acc[4][4];
    #pragma unroll
    for (int mt = 0; mt < 4; ++mt)
      #pragma unroll
      for (int nt = 0; nt < 4; ++nt)
        acc[mt][nt] = (f32x4){0.f, 0.f, 0.f, 0.f};

    // ---- x MFMAs (overlap the first poll round trip) ----
    #pragma unroll
    for (int kt = 0; kt < KTW; ++kt){
      const int kg = (w*KTW + kt) * 32;
      if (kg < KX){
        #pragma unroll
        for (int mt = 0; mt < 4; ++mt)
          #pragma unroll
          for (int nt = 0; nt < 4; ++nt)
            acc[mt][nt] = __builtin_amdgcn_mfma_f32_16x16x32_bf16(xreg[kt][mt], bfr[kt][nt], acc[mt][nt], 0, 0, 0);
      }
    }

    if (polling){
      // ---- detect: all NF flags >= s (coalesced 2-line gather) ----
      const unsigned tgt = (unsigned)s;
      for (;;){
        unsigned v = pv0;
        if constexpr (NF > 64) v = pv1 < v ? pv1 : v;
        if (__all(v >= tgt)) break;
        __builtin_amdgcn_s_sleep(1);
        pv0 = __hip_atomic_load(&flg[lane], __ATOMIC_RELAXED, __HIP_MEMORY_SCOPE_AGENT);
        if constexpr (NF > 64)
          pv1 = __hip_atomic_load(&flg[lane + 64], __ATOMIC_RELAXED, __HIP_MEMORY_SCOPE_AGENT);
      }
      __builtin_amdgcn_sched_barrier(0);
      // ---- h loads + h MFMAs ----
      #pragma unroll
      for (int kt = 0; kt < KTW; ++kt){
        const int kg = (w*KTW + kt) * 32;
        if (kg >= KX){
          #pragma unroll
          for (int mt = 0; mt < 4; ++mt){
            const ull* hp = (const ull*)
                (hb + (size_t)par*64*U + (size_t)(mt*16 + arow)*U + (kg - KX + kgrp));
            ulonglong2 u;
            u.x = __hip_atomic_load(hp,     __ATOMIC_RELAXED, __HIP_MEMORY_SCOPE_AGENT);
            u.y = __hip_atomic_load(hp + 1, __ATOMIC_RELAXED, __HIP_MEMORY_SCOPE_AGENT);
            short8 a = __builtin_bit_cast(short8, u);
            #pragma unroll
            for (int nt = 0; nt < 4; ++nt)
              acc[mt][nt] = __builtin_amdgcn_mfma_f32_16x16x32_bf16(a, bfr[kt][nt], acc[mt][nt], 0, 0, 0);
          }
        }
      }
    }

    // ---- D-frag scatter (b128) ----
    #pragma unroll
    for (int mt = 0; mt < 4; ++mt)
      #pragma unroll
      for (int nt = 0; nt < 4; ++nt)
        *(f32x4*)&part[w][nt*16 + arow][mt*16 + rquad] = acc[mt][nt];

    bar_lds();           // scatter visible to gate readers (LDS-only)

    // ---- gate phase: LDS reduce ----
    f32x4 zg[4];
    #pragma unroll
    for (int g = 0; g < 4; ++g){
      const int cb = g*16 + u_l;
      f32x4 v = *(const f32x4*)&part[0][cb][rb];
      #pragma unroll
      for (int ww = 1; ww < 4; ++ww)
        v += *(const f32x4*)&part[ww][cb][rb];
      zg[g] = v;
    }

    bar_lds();           // gate reads done -> next scatter safe (LDS-only)

    #pragma unroll
    for (int r = 0; r < 4; ++r){
      float ig = sigm (zg[0][r] + bz[0]);
      float fg = sigm (zg[1][r] + bz[1]);
      float gg = tanh_(zg[2][r] + bz[2]);
      float og = sigm (zg[3][r] + bz[3]);
      float cn = fg * c[r] + ig * gg;
      float hn = og * tanh_(cn);
      bool m  = (t < sz[r]);
      c[r] = m ? cn : c[r];
      float h = m ? hn : hreg[r];
      hreg[r] = h;
      if (s != T - 1)
        __hip_atomic_store(&hb[(size_t)(par ^ 1)*64*U + (size_t)(rb + r)*U + ug],
                           (unsigned short)f2bf(h),
                           __ATOMIC_RELAXED, __HIP_MEMORY_SCOPE_AGENT);
    }

    if (s != T - 1){
      // ---- per-wave publish: drain own h-store acks, then flag store ----
      __builtin_amdgcn_sched_barrier(0);
      asm volatile("s_waitcnt vmcnt(0)" ::: "memory");
      __builtin_amdgcn_sched_barrier(0);
      if (lane == 0)
        __hip_atomic_store(&flg[wg*4 + w], (unsigned)(s + 1),
                           __ATOMIC_RELAXED, __HIP_MEMORY_SCOPE_AGENT);
      __builtin_amdgcn_sched_barrier(0);
    }

    // ---- out stores AFTER publish (acks never in the chain) ----
    #pragma unroll
    for (int r = 0; r < 4; ++r)
      outp[((size_t)(rb + r)*T + t)*U + ug] = hreg[r];

    // ---- x prefetch for next step ----
    if (s != T - 1){
      const int tn = dir ? t - 1 : t + 1;
      #pragma unroll
      for (int kt = 0; kt < KTW; ++kt){
        const int kg = (w*KTW + kt) * 32;
        if (kg < KX){
          #pragma unroll
          for (int mt = 0; mt < 4; ++mt)
            xreg[kt][mt] = *(const short8*)(xab + ((size_t)((mt*16 + arow)*T + tn))*KX + (kg + kgrp));
        }
      }
    }
  }
}

// ---------------- launch ----------------

extern "C" void kernel_launch(void* const* d_in, const int* in_sizes, int n_in,
                              void* d_out, int out_size, void* d_ws, size_t ws_size,
                              hipStream_t stream){
  const float* x      = (const float*)d_in[0];
  const int*   sizes  = (const int*)  d_in[1];
  const float* enc_kf = (const float*)d_in[2];
  const float* enc_rf = (const float*)d_in[3];
  const float* enc_bf = (const float*)d_in[4];
  const float* enc_kb = (const float*)d_in[5];
  const float* enc_rb = (const float*)d_in[6];
  const float* enc_bb = (const float*)d_in[7];
  const float* dec_kf = (const float*)d_in[8];
  const float* dec_rf = (const float*)d_in[9];
  const float* dec_bf = (const float*)d_in[10];
  const float* dec_kb = (const float*)d_in[11];
  const float* dec_rb = (const float*)d_in[12];
  const float* dec_bb = (const float*)d_in[13];
  float* out = (float*)d_out;
  char*  ws  = (char*)d_ws;

  const size_t o_xbf   = 0;                        // 33,554,432  x bf16
  const size_t o_esum  = o_xbf   + 33554432ull;    // 16,777,216  enc sum bf16
  const size_t o_pBe   = o_esum  + 16777216ull;    //  3,145,728  packed enc
  const size_t o_pBd   = o_pBe   + 3145728ull;     //  6,291,456  packed dec
  const size_t o_hfe   = o_pBd   + 6291456ull;     // 33,554,432  enc fwd h f32
  const size_t o_hbe   = o_hfe   + 33554432ull;    // 33,554,432  enc bwd h f32
  const size_t o_hbd   = o_hbe   + 33554432ull;    // 67,108,864  dec bwd h f32
  const size_t o_hbufe = o_hbd   + 67108864ull;    //    131,072  enc h exchange
  const size_t o_hbufd = o_hbufe + 131072ull;      //    262,144  dec h exchange
  const size_t o_flge  = o_hbufd + 262144ull;      //      1,024  enc flags (2 dirs x 128 u32)
  const size_t o_flgd  = o_flge  + 1024ull;        //      1,024  dec flags
  const size_t total   = o_flgd  + 1024ull;
  if (ws_size < total) return;

  unsigned short* xbf   = (unsigned short*)(ws + o_xbf);
  unsigned short* esum  = (unsigned short*)(ws + o_esum);
  unsigned short* pBe   = (unsigned short*)(ws + o_pBe);
  unsigned short* pBd   = (unsigned short*)(ws + o_pBd);
  float*          hfe   = (float*)(ws + o_hfe);
  float*          hbe   = (float*)(ws + o_hbe);
  float*          hbd   = (float*)(ws + o_hbd);
  unsigned short* hbufe = (unsigned short*)(ws + o_hbufe);
  unsigned short* hbufd = (unsigned short*)(ws + o_hbufd);
  unsigned*       flge  = (unsigned*)(ws + o_flge);
  unsigned*       flgd  = (unsigned*)(ws + o_flgd);

  // zero flags every call (deterministic graph replays)
  hipMemsetAsync(ws + o_flge, 0, 2048ull, stream);

  // x -> bf16
  k_f32_to_bf16<<<2048, 256, 0, stream>>>(x, xbf, 64*512*512);

  // pack weights (blocked K split)
  k_pack<<<2048, 256, 0, stream>>>(enc_kf, enc_rf, enc_kb, enc_rb, pBe, 786432, 512, 256);
  k_pack<<<2048, 256, 0, stream>>>(dec_kf, dec_rf, dec_kb, dec_rb, pBd, 1572864, 256, 512);

  // encoder bilstm (fwd 16 WGs + bwd 16 WGs)
  lstm_rec<512, 256, 16><<<32, 256, 0, stream>>>(xbf, pBe, enc_bf, enc_bb, sizes,
                                                 hbufe, flge, hfe, hbe);
  // enc_sum = bf16(hf + hb)
  k_add_bf16<<<2048, 256, 0, stream>>>(hfe, hbe, esum, 64*512*256);

  // decoder bilstm: fwd writes d_out directly, bwd to ws
  lstm_rec<256, 512, 32><<<64, 256, 0, stream>>>(esum, pBd, dec_bf, dec_bb, sizes,
                                                 hbufd, flgd, out, hbd);
  // d_out += dec bwd
  k_add_f32<<<2048, 256, 0, stream>>>(out, hbd, 64*512*512);
}

// Round 12
// 8589.387 us; speedup vs baseline: 1.6642x; 1.0008x over previous
//
#include <hip/hip_runtime.h>
#include <stdint.h>

using short8 = __attribute__((ext_vector_type(8))) short;
using f32x4  = __attribute__((ext_vector_type(4))) float;
typedef unsigned long long ull;

#define DEV static __device__ __forceinline__

DEV unsigned short f2bf(float f){
  unsigned u = __builtin_bit_cast(unsigned, f);
  u = (u + 0x7FFFu + ((u >> 16) & 1u)) >> 16;
  return (unsigned short)u;
}
DEV float bf2f(unsigned short v){
  return __builtin_bit_cast(float, ((unsigned)v) << 16);
}
DEV float sigm(float x){
  float e = __builtin_amdgcn_exp2f(-1.4426950408889634f * x);
  return __builtin_amdgcn_rcpf(1.0f + e);
}
DEV float tanh_(float x){
  float e = __builtin_amdgcn_exp2f(2.885390081777927f * x); // exp(2x)
  return 1.0f - 2.0f * __builtin_amdgcn_rcpf(e + 1.0f);
}
DEV void bar_lds(){
  __builtin_amdgcn_sched_barrier(0);
  asm volatile("s_waitcnt lgkmcnt(0)" ::: "memory");
  __builtin_amdgcn_s_barrier();
  __builtin_amdgcn_sched_barrier(0);
}
// enc packed-column mapping: colp -> (gate g, unit u). Used consistently by
// the xz GEMM pack, the recurrence pack, bias load and gate math.
DEV void colmap_e(int colp, int& g, int& u){
  int w = colp >> 7, r = colp & 127, nt = r >> 4, l = r & 15;
  g = nt >> 1; u = w*32 + ((nt & 1) << 4) + l;
}

// ---------------- aux kernels ----------------

__global__ void k_f32_to_bf16(const float* __restrict__ in, unsigned short* __restrict__ out, int n){
  int stride = gridDim.x * blockDim.x * 4;
  for (int i = (blockIdx.x * blockDim.x + threadIdx.x) * 4; i < n; i += stride){
    float4 v = *(const float4*)(in + i);
    ushort4 o4;
    o4.x = f2bf(v.x); o4.y = f2bf(v.y); o4.z = f2bf(v.z); o4.w = f2bf(v.w);
    *(ushort4*)(out + i) = o4;
  }
}

// f32 + f32 -> bf16 (fallback enc sum)
__global__ void k_add_bf16(const float* __restrict__ a, const float* __restrict__ b,
                           unsigned short* __restrict__ out, int n){
  int stride = gridDim.x * blockDim.x * 4;
  for (int i = (blockIdx.x * blockDim.x + threadIdx.x) * 4; i < n; i += stride){
    float4 va = *(const float4*)(a + i);
    float4 vb = *(const float4*)(b + i);
    ushort4 o4;
    o4.x = f2bf(va.x + vb.x); o4.y = f2bf(va.y + vb.y);
    o4.z = f2bf(va.z + vb.z); o4.w = f2bf(va.w + vb.w);
    *(ushort4*)(out + i) = o4;
  }
}

// bf16 + bf16 -> bf16 (new enc sum)
__global__ void k_add_bb(const unsigned short* __restrict__ a, const unsigned short* __restrict__ b,
                         unsigned short* __restrict__ out, int n){
  int stride = gridDim.x * blockDim.x * 8;
  for (int i = (blockIdx.x * blockDim.x + threadIdx.x) * 8; i < n; i += stride){
    short8 va = *(const short8*)(a + i);
    short8 vb = *(const short8*)(b + i);
    short8 o;
    #pragma unroll
    for (int j = 0; j < 8; ++j)
      o[j] = (short)f2bf(bf2f((unsigned short)va[j]) + bf2f((unsigned short)vb[j]));
    *(short8*)(out + i) = o;
  }
}

__global__ void k_add_f32(float* __restrict__ o, const float* __restrict__ b, int n){
  int stride = gridDim.x * blockDim.x * 4;
  for (int i = (blockIdx.x * blockDim.x + threadIdx.x) * 4; i < n; i += stride){
    float4 vo = *(const float4*)(o + i);
    float4 vb = *(const float4*)(b + i);
    vo.x += vb.x; vo.y += vb.y; vo.z += vb.z; vo.w += vb.w;
    *(float4*)(o + i) = vo;
  }
}

// R5 pack: [k; r] fused, blocked K split (dec + fallback enc)
__global__ void k_pack(const float* __restrict__ k0, const float* __restrict__ r0,
                       const float* __restrict__ k1, const float* __restrict__ r1,
                       unsigned short* __restrict__ out, int E, int KX, int U){
  int n = 2 * E;
  int stride = gridDim.x * blockDim.x;
  for (int i = blockIdx.x * blockDim.x + threadIdx.x; i < n; i += stride){
    int d = i / E, r = i % E;
    const float* Km = d ? k1 : k0;
    const float* Rm = d ? r1 : r0;
    int j    = r & 7;  int q = r >> 3;
    int lane = q & 63; q >>= 6;
    int nt   = q & 3;  q >>= 2;
    int kt   = q % 6;  q /= 6;
    int w    = q & 3;  int wg = q >> 2;
    int k    = (w*6 + kt)*32 + ((lane >> 4) << 3) + j;
    int col  = nt * U + wg*16 + (lane & 15);
    float v  = (k < KX) ? Km[(size_t)k * (4*U) + col]
                        : Rm[(size_t)(k - KX) * (4*U) + col];
    out[i] = f2bf(v);
  }
}

// pack enc k (input proj) for the xz GEMM: [dir][ct16][w4][kt4][nt4][lane][8]
__global__ void k_pack_ge(const float* __restrict__ kf, const float* __restrict__ kb,
                          unsigned short* __restrict__ out){
  int n = 2 * 524288;
  int stride = gridDim.x * blockDim.x;
  for (int i = blockIdx.x * blockDim.x + threadIdx.x; i < n; i += stride){
    int j    = i & 7;
    int lane = (i >> 3) & 63;
    int nt   = (i >> 9) & 3;
    int kt   = (i >> 11) & 3;
    int w    = (i >> 13) & 3;
    int ct   = (i >> 15) & 15;
    int dir  = i >> 19;
    int k    = (w*4 + kt)*32 + ((lane >> 4) << 3) + j;
    int colp = ct*64 + nt*16 + (lane & 15);
    int g, u; colmap_e(colp, g, u);
    const float* K = dir ? kb : kf;
    out[i] = f2bf(K[(size_t)k * 1024 + g*256 + u]);
  }
}

// pack enc r (recurrent) for the zero-sync recurrence: [dir][w8][kt8][nt8][lane][8]
__global__ void k_pack_re(const float* __restrict__ rf, const float* __restrict__ rb,
                          unsigned short* __restrict__ out){
  int n = 2 * 262144;
  int stride = gridDim.x * blockDim.x;
  for (int i = blockIdx.x * blockDim.x + threadIdx.x; i < n; i += stride){
    int j    = i & 7;
    int lane = (i >> 3) & 63;
    int nt   = (i >> 9) & 7;
    int kt   = (i >> 12) & 7;
    int w    = (i >> 15) & 7;
    int dir  = i >> 18;
    int k    = kt*32 + ((lane >> 4) << 3) + j;       // source h unit (K dim)
    int colp = w*128 + nt*16 + (lane & 15);
    int g, u; colmap_e(colp, g, u);
    const float* R = dir ? rb : rf;
    out[i] = f2bf(R[(size_t)k * 1024 + g*256 + u]);
  }
}

// xz GEMM: xzt[dir][1024 colp][t*64 + b] (bf16) = x @ k_enc (no bias).
// grid = 2 dirs x 512 t x 16 coltiles; 256 thr; B-frags in regs, LDS reduce.
__global__ __launch_bounds__(256, 1)
void k_gemm_xz(const unsigned short* __restrict__ xab,   // [64][512][512] bf16
               const unsigned short* __restrict__ pBg,
               unsigned short* __restrict__ xzt){
  const int tid  = threadIdx.x;
  const int w    = tid >> 6;
  const int lane = tid & 63;
  const int ct   = blockIdx.x & 15;
  const int t    = (blockIdx.x >> 4) & 511;
  const int dir  = blockIdx.x >> 13;

  short8 bfr[4][4];
  #pragma unroll
  for (int kt = 0; kt < 4; ++kt)
    #pragma unroll
    for (int nt = 0; nt < 4; ++nt)
      bfr[kt][nt] = *(const short8*)(pBg + (size_t)((((dir*16 + ct)*4 + w)*4 + kt)*4 + nt)*512 + lane*8);

  const int arow = lane & 15;
  const int kgrp = (lane >> 4) * 8;
  const int rquad = (lane >> 4) * 4;

  f32x4 acc[4][4];
  #pragma unroll
  for (int mt = 0; mt < 4; ++mt)
    #pragma unroll
    for (int nt = 0; nt < 4; ++nt)
      acc[mt][nt] = (f32x4){0.f,0.f,0.f,0.f};

  #pragma unroll
  for (int kt = 0; kt < 4; ++kt){
    const int kg = (w*4 + kt)*32;
    #pragma unroll
    for (int mt = 0; mt < 4; ++mt){
      const int row = mt*16 + arow;   // batch row
      short8 a = *(const short8*)(xab + ((size_t)(row*512 + t))*512 + kg + kgrp);
      #pragma unroll
      for (int nt = 0; nt < 4; ++nt)
        acc[mt][nt] = __builtin_amdgcn_mfma_f32_16x16x32_bf16(a, bfr[kt][nt], acc[mt][nt], 0, 0, 0);
    }
  }

  __shared__ float part[4][64][68];
  #pragma unroll
  for (int mt = 0; mt < 4; ++mt)
    #pragma unroll
    for (int nt = 0; nt < 4; ++nt)
      *(f32x4*)&part[w][nt*16 + arow][mt*16 + rquad] = acc[mt][nt];

  __syncthreads();

  const int cl = tid & 63;
  const int rq = (tid >> 6) * 16;
  unsigned short ov[16];
  #pragma unroll
  for (int q = 0; q < 4; ++q){
    f32x4 v = *(const f32x4*)&part[0][cl][rq + q*4];
    #pragma unroll
    for (int ww = 1; ww < 4; ++ww)
      v += *(const f32x4*)&part[ww][cl][rq + q*4];
    #pragma unroll
    for (int r = 0; r < 4; ++r) ov[q*4 + r] = f2bf(v[r]);
  }
  size_t base = ((size_t)(dir*1024 + ct*64 + cl))*32768 + (size_t)t*64 + rq;
  *(short8*)(xzt + base)     = *(short8*)&ov[0];
  *(short8*)(xzt + base + 8) = *(short8*)&ov[8];
}

// ---------------- enc recurrence: batch-split, ZERO inter-WG sync ----------------
// grid = 8 blocks (2 dirs x 4 row-groups of 16), 512 threads (8 waves).
// Full r_enc in registers (256 VGPR/lane B-frags); h broadcast via LDS with
// ONE LDS-only barrier per step. No global sync of any kind.
__global__ __launch_bounds__(512, 1)
void k_enc_rec(const unsigned short* __restrict__ xzt,   // [2][1024][32768] bf16
               const unsigned short* __restrict__ pBr,
               const float* __restrict__ bias_f,
               const float* __restrict__ bias_b,
               const int*   __restrict__ sizes,
               unsigned short* __restrict__ out_f,       // [64][512][256] bf16
               unsigned short* __restrict__ out_b){
  constexpr int T = 512;
  const int tid   = threadIdx.x;
  const int w     = tid >> 6;        // 0..7
  const int lane  = tid & 63;
  const int l15   = lane & 15;
  const int dir   = (int)blockIdx.x >> 2;
  const int rbase = ((int)blockIdx.x & 3) * 16;

  // B fragments: full r for this wave's 128 packed cols (256 VGPR)
  short8 bfr[8][8];
  #pragma unroll
  for (int kt = 0; kt < 8; ++kt)
    #pragma unroll
    for (int nt = 0; nt < 8; ++nt)
      bfr[kt][nt] = *(const short8*)(pBr + (size_t)(((dir*8 + w)*8 + kt)*8 + nt)*512 + lane*8);

  const float* bias = dir ? bias_b : bias_f;
  unsigned short* outp = dir ? out_b : out_f;

  float bz[2][4];
  #pragma unroll
  for (int us = 0; us < 2; ++us){
    const int u = w*32 + us*16 + l15;
    #pragma unroll
    for (int g = 0; g < 4; ++g) bz[us][g] = bias[g*256 + u];
  }
  int sz[4];
  #pragma unroll
  for (int r2 = 0; r2 < 4; ++r2) sz[r2] = sizes[rbase + (lane >> 4)*4 + r2];

  float c[2][4], hv[2][4];
  #pragma unroll
  for (int us = 0; us < 2; ++us)
    #pragma unroll
    for (int r2 = 0; r2 < 4; ++r2){ c[us][r2] = 0.f; hv[us][r2] = 0.f; }

  __shared__ unsigned short hl[2][16][264];   // [parity][row][unit + pad]
  for (int i = tid; i < 16*264; i += 512) ((unsigned short*)hl[0])[i] = 0;
  __syncthreads();

  const size_t xzdir = (size_t)dir * 1024 * 32768;

  for (int s = 0; s < T; ++s){
    const int t   = dir ? (T - 1 - s) : s;
    const int par = s & 1;

    // acc init = xz (bf16), aligned 8B loads: 4 consecutive batch rows
    f32x4 acc[8];
    #pragma unroll
    for (int nt = 0; nt < 8; ++nt){
      const int colp = w*128 + nt*16 + l15;
      const unsigned short* p = xzt + xzdir + (size_t)colp*32768 + (size_t)t*64 + rbase + ((lane >> 4) << 2);
      ushort4 xv = *(const ushort4*)p;
      acc[nt] = (f32x4){bf2f(xv.x), bf2f(xv.y), bf2f(xv.z), bf2f(xv.w)};
    }

    // h @ r: A from LDS (h of step s-1), 64 MFMAs
    #pragma unroll
    for (int kt = 0; kt < 8; ++kt){
      short8 a = *(const short8*)&hl[par][l15][kt*32 + ((lane >> 4) << 3)];
      #pragma unroll
      for (int nt = 0; nt < 8; ++nt)
        acc[nt] = __builtin_amdgcn_mfma_f32_16x16x32_bf16(a, bfr[kt][nt], acc[nt], 0, 0, 0);
    }

    // gate math: thread owns 2 units x 4 rows (all 4 gates in-thread)
    #pragma unroll
    for (int us = 0; us < 2; ++us){
      const int u = w*32 + us*16 + l15;
      #pragma unroll
      for (int r2 = 0; r2 < 4; ++r2){
        float zi = acc[0 + us][r2] + bz[us][0];
        float zf = acc[2 + us][r2] + bz[us][1];
        float zg = acc[4 + us][r2] + bz[us][2];
        float zo = acc[6 + us][r2] + bz[us][3];
        float ig = sigm(zi), fg = sigm(zf), gg = tanh_(zg), og = sigm(zo);
        float cn = fg * c[us][r2] + ig * gg;
        float hn = og * tanh_(cn);
        bool m = (t < sz[r2]);
        c[us][r2] = m ? cn : c[us][r2];
        float h = m ? hn : hv[us][r2];
        hv[us][r2] = h;
        unsigned short hb16 = f2bf(h);
        const int rloc = (lane >> 4)*4 + r2;
        hl[par ^ 1][rloc][u] = hb16;
        outp[((size_t)((rbase + rloc)*512) + t)*256 + u] = hb16;
      }
    }

    bar_lds();   // h(par^1) visible to all waves; next step reads it
  }
}

// ---------------- R5 persistent recurrence (dec + fallback enc) ----------------
template<int KX, int U, int WGS>
__global__ __launch_bounds__(256, 1)
void lstm_rec(const unsigned short* __restrict__ xab,
              const unsigned short* __restrict__ packedB,
              const float* __restrict__ bias_f,
              const float* __restrict__ bias_b,
              const int*   __restrict__ sizes,
              unsigned short* __restrict__ hbuf,
              unsigned int*  __restrict__ counters,
              float* __restrict__ out_f,
              float* __restrict__ out_b)
{
  constexpr int KTW = 6;
  constexpr int T   = 512;

  const int tid  = threadIdx.x;
  const int w    = tid >> 6;
  const int lane = tid & 63;
  const int dir  = (blockIdx.x >= WGS) ? 1 : 0;
  const int wg   = dir ? (int)blockIdx.x - WGS : (int)blockIdx.x;

  const unsigned short* pB = packedB + (size_t)dir * ((size_t)WGS*4*KTW*4*512)
                                     + (size_t)((wg*4 + w)*KTW)*4*512;
  unsigned short* hb  = hbuf + (size_t)dir * (2*64*U);
  unsigned int*   cnt = counters + dir * 32;
  const float* bias = dir ? bias_b : bias_f;
  float* outp       = dir ? out_b : out_f;

  const bool has_h = ((w*KTW + KTW - 1) * 32) >= KX;

  short8 bfr[KTW][4];
  #pragma unroll
  for (int kt = 0; kt < KTW; ++kt)
    #pragma unroll
    for (int nt = 0; nt < 4; ++nt)
      bfr[kt][nt] = *(const short8*)(pB + ((kt*4 + nt)*512) + lane*8);

  const int u_l = tid & 15;
  const int rb  = (tid >> 4) * 4;
  const int ug  = wg*16 + u_l;
  float bz[4]; int sz[4];
  #pragma unroll
  for (int g = 0; g < 4; ++g) bz[g] = bias[g*U + ug];
  #pragma unroll
  for (int r = 0; r < 4; ++r) sz[r] = sizes[rb + r];
  float c[4]    = {0.f,0.f,0.f,0.f};
  float hreg[4] = {0.f,0.f,0.f,0.f};

  __shared__ float part[4][64][68];

  const int arow  = lane & 15;
  const int kgrp  = (lane >> 4) * 8;
  const int rquad = (lane >> 4) * 4;

  short8 xreg[KTW][4];
  {
    const int t0 = dir ? T - 1 : 0;
    #pragma unroll
    for (int kt = 0; kt < KTW; ++kt){
      const int kg = (w*KTW + kt) * 32;
      if (kg < KX){
        #pragma unroll
        for (int mt = 0; mt < 4; ++mt)
          xreg[kt][mt] = *(const short8*)(xab + ((size_t)((mt*16 + arow)*T + t0))*KX + (kg + kgrp));
      }
    }
  }

  for (int s = 0; s < T; ++s){
    const int t   = dir ? (T - 1 - s) : s;
    const int par = s & 1;

    f32x4 acc[4][4];
    #pragma unroll
    for (int mt = 0; mt < 4; ++mt)
      #pragma unroll
      for (int nt = 0; nt < 4; ++nt)
        acc[mt][nt] = (f32x4){0.f, 0.f, 0.f, 0.f};

    #pragma unroll
    for (int kt = 0; kt < KTW; ++kt){
      const int kg = (w*KTW + kt) * 32;
      if (kg < KX){
        #pragma unroll
        for (int mt = 0; mt < 4; ++mt)
          #pragma unroll
          for (int nt = 0; nt < 4; ++nt)
            acc[mt][nt] = __builtin_amdgcn_mfma_f32_16x16x32_bf16(xreg[kt][mt], bfr[kt][nt], acc[mt][nt], 0, 0, 0);
      }
    }

    if (s > 0 && has_h){
      const unsigned tgt = (unsigned)WGS * (unsigned)s;
      for (;;){
        unsigned v = __hip_atomic_load(cnt, __ATOMIC_RELAXED, __HIP_MEMORY_SCOPE_AGENT);
        if (v >= tgt) break;
        __builtin_amdgcn_s_sleep(1);
      }
      __builtin_amdgcn_sched_barrier(0);
      #pragma unroll
      for (int kt = 0; kt < KTW; ++kt){
        const int kg = (w*KTW + kt) * 32;
        if (kg >= KX){
          #pragma unroll
          for (int mt = 0; mt < 4; ++mt){
            const ull* hp = (const ull*)
                (hb + (size_t)par*64*U + (size_t)(mt*16 + arow)*U + (kg - KX + kgrp));
            ulonglong2 u;
            u.x = __hip_atomic_load(hp,     __ATOMIC_RELAXED, __HIP_MEMORY_SCOPE_AGENT);
            u.y = __hip_atomic_load(hp + 1, __ATOMIC_RELAXED, __HIP_MEMORY_SCOPE_AGENT);
            short8 a = __builtin_bit_cast(short8, u);
            #pragma unroll
            for (int nt = 0; nt < 4; ++nt)
              acc[mt][nt] = __builtin_amdgcn_mfma_f32_16x16x32_bf16(a, bfr[kt][nt], acc[mt][nt], 0, 0, 0);
          }
        }
      }
    }

    #pragma unroll
    for (int mt = 0; mt < 4; ++mt)
      #pragma unroll
      for (int nt = 0; nt < 4; ++nt)
        *(f32x4*)&part[w][nt*16 + arow][mt*16 + rquad] = acc[mt][nt];

    __syncthreads();

    f32x4 zg[4];
    #pragma unroll
    for (int g = 0; g < 4; ++g){
      const int cb = g*16 + u_l;
      f32x4 v = *(const f32x4*)&part[0][cb][rb];
      #pragma unroll
      for (int ww = 1; ww < 4; ++ww)
        v += *(const f32x4*)&part[ww][cb][rb];
      zg[g] = v;
    }

    #pragma unroll
    for (int r = 0; r < 4; ++r){
      float ig = sigm (zg[0][r] + bz[0]);
      float fg = sigm (zg[1][r] + bz[1]);
      float gg = tanh_(zg[2][r] + bz[2]);
      float og = sigm (zg[3][r] + bz[3]);
      float cn = fg * c[r] + ig * gg;
      float hn = og * tanh_(cn);
      bool m  = (t < sz[r]);
      c[r] = m ? cn : c[r];
      float h = m ? hn : hreg[r];
      hreg[r] = h;
      __hip_atomic_store(&hb[(size_t)(par ^ 1)*64*U + (size_t)(rb + r)*U + ug],
                         (unsigned short)f2bf(h),
                         __ATOMIC_RELAXED, __HIP_MEMORY_SCOPE_AGENT);
    }

    __syncthreads();

    if (s != T - 1){
      if (tid == 0) atomicAdd(cnt, 1u);
    }

    #pragma unroll
    for (int r = 0; r < 4; ++r)
      outp[((size_t)(rb + r)*T + t)*U + ug] = hreg[r];

    if (s != T - 1){
      const int tn = dir ? t - 1 : t + 1;
      #pragma unroll
      for (int kt = 0; kt < KTW; ++kt){
        const int kg = (w*KTW + kt) * 32;
        if (kg < KX){
          #pragma unroll
          for (int mt = 0; mt < 4; ++mt)
            xreg[kt][mt] = *(const short8*)(xab + ((size_t)((mt*16 + arow)*T + tn))*KX + (kg + kgrp));
        }
      }
    }
  }
}

// ---------------- launch ----------------

extern "C" void kernel_launch(void* const* d_in, const int* in_sizes, int n_in,
                              void* d_out, int out_size, void* d_ws, size_t ws_size,
                              hipStream_t stream){
  const float* x      = (const float*)d_in[0];
  const int*   sizes  = (const int*)  d_in[1];
  const float* enc_kf = (const float*)d_in[2];
  const float* enc_rf = (const float*)d_in[3];
  const float* enc_bf = (const float*)d_in[4];
  const float* enc_kb = (const float*)d_in[5];
  const float* enc_rb = (const float*)d_in[6];
  const float* enc_bb = (const float*)d_in[7];
  const float* dec_kf = (const float*)d_in[8];
  const float* dec_rf = (const float*)d_in[9];
  const float* dec_bf = (const float*)d_in[10];
  const float* dec_kb = (const float*)d_in[11];
  const float* dec_rb = (const float*)d_in[12];
  const float* dec_bb = (const float*)d_in[13];
  float* out = (float*)d_out;
  char*  ws  = (char*)d_ws;

  // ---- new-path layout (~295 MB) ----
  const size_t o_xbf  = 0;                        // 33,554,432
  const size_t o_esum = o_xbf  + 33554432ull;     // 16,777,216
  const size_t o_pBd  = o_esum + 16777216ull;     //  6,291,456
  const size_t o_ehf  = o_pBd  + 6291456ull;      // 16,777,216 (bf16)
  const size_t o_ehb  = o_ehf  + 16777216ull;     // 16,777,216 (bf16)
  const size_t o_hbd  = o_ehb  + 16777216ull;     // 67,108,864
  const size_t o_hbufd= o_hbd  + 67108864ull;     //    262,144
  const size_t o_cntd = o_hbufd+ 262144ull;       //      4,096
  const size_t o_pBg  = o_cntd + 4096ull;         //  2,097,152
  const size_t o_pBr  = o_pBg  + 2097152ull;      //  1,048,576
  const size_t o_xzt  = o_pBr  + 1048576ull;      // 134,217,728
  const size_t NEWTOT = o_xzt  + 134217728ull;    // 294,916,096

  unsigned short* xbf  = (unsigned short*)(ws + o_xbf);
  unsigned short* esum = (unsigned short*)(ws + o_esum);
  unsigned short* pBd  = (unsigned short*)(ws + o_pBd);
  float*          hbd  = (float*)(ws + o_hbd);
  unsigned short* hbufd= (unsigned short*)(ws + o_hbufd);
  unsigned int*   cntd = (unsigned int*)(ws + o_cntd);

  if (ws_size >= NEWTOT){
    unsigned short* ehf = (unsigned short*)(ws + o_ehf);
    unsigned short* ehb = (unsigned short*)(ws + o_ehb);
    unsigned short* pBg = (unsigned short*)(ws + o_pBg);
    unsigned short* pBr = (unsigned short*)(ws + o_pBr);
    unsigned short* xzt = (unsigned short*)(ws + o_xzt);

    hipMemsetAsync(ws + o_cntd, 0, 4096ull, stream);

    k_f32_to_bf16<<<2048, 256, 0, stream>>>(x, xbf, 64*512*512);
    k_pack_ge<<<1024, 256, 0, stream>>>(enc_kf, enc_kb, pBg);
    k_pack_re<<<512, 256, 0, stream>>>(enc_rf, enc_rb, pBr);
    k_pack<<<2048, 256, 0, stream>>>(dec_kf, dec_rf, dec_kb, dec_rb, pBd, 1572864, 256, 512);

    // xz = x @ k_enc (both dirs), transposed bf16
    k_gemm_xz<<<16384, 256, 0, stream>>>(xbf, pBg, xzt);
    // zero-sync batch-split enc recurrence
    k_enc_rec<<<8, 512, 0, stream>>>(xzt, pBr, enc_bf, enc_bb, sizes, ehf, ehb);
    // esum = ehf + ehb (bf16)
    k_add_bb<<<2048, 256, 0, stream>>>(ehf, ehb, esum, 64*512*256);
    // dec (R5 protocol, unchanged)
    lstm_rec<256, 512, 32><<<64, 256, 0, stream>>>(esum, pBd, dec_bf, dec_bb, sizes,
                                                   hbufd, cntd, out, hbd);
    k_add_f32<<<2048, 256, 0, stream>>>(out, hbd, 64*512*512);
  } else {
    // ---- fallback: full R5 path (~194 MB) ----
    const size_t f_pBe   = o_pBr;                      // reuse region (fits: pBr+xzt area)
    // R5-style layout carved after o_cntd:
    const size_t f_hfe   = o_cntd + 4096ull;           // 33,554,432 f32
    const size_t f_hbe   = f_hfe  + 33554432ull;       // 33,554,432 f32
    const size_t f_hbufe = f_hbe  + 33554432ull;       //    131,072
    const size_t f_cnte  = f_hbufe+ 131072ull;         //      4,096
    const size_t f_pBe2  = f_cnte + 4096ull;           //  3,145,728
    const size_t FTOT    = f_pBe2 + 3145728ull;
    if (ws_size < FTOT) return;
    (void)f_pBe;

    float* hfe = (float*)(ws + f_hfe);
    float* hbe = (float*)(ws + f_hbe);
    unsigned short* hbufe = (unsigned short*)(ws + f_hbufe);
    unsigned int* cnte = (unsigned int*)(ws + f_cnte);
    unsigned short* pBe = (unsigned short*)(ws + f_pBe2);

    hipMemsetAsync(ws + o_cntd, 0, 4096ull, stream);
    hipMemsetAsync(ws + f_cnte, 0, 4096ull, stream);

    k_f32_to_bf16<<<2048, 256, 0, stream>>>(x, xbf, 64*512*512);
    k_pack<<<2048, 256, 0, stream>>>(enc_kf, enc_rf, enc_kb, enc_rb, pBe, 786432, 512, 256);
    k_pack<<<2048, 256, 0, stream>>>(dec_kf, dec_rf, dec_kb, dec_rb, pBd, 1572864, 256, 512);

    lstm_rec<512, 256, 16><<<32, 256, 0, stream>>>(xbf, pBe, enc_bf, enc_bb, sizes,
                                                   hbufe, cnte, hfe, hbe);
    k_add_bf16<<<2048, 256, 0, stream>>>(hfe, hbe, esum, 64*512*256);
    lstm_rec<256, 512, 32><<<64, 256, 0, stream>>>(esum, pBd, dec_bf, dec_bb, sizes,
                                                   hbufd, cntd, out, hbd);
    k_add_f32<<<2048, 256, 0, stream>>>(out, hbd, 64*512*512);
  }
}